// Round 2
// baseline (1211.566 us; speedup 1.0000x reference)
//
#include <hip/hip_runtime.h>

#define NN   50000
#define EE   600000
#define DINK 518
#define DD   128
#define NEG_SLOPE 0.2f

// ---------------- GEMM: C = act(A[M,K] @ B[K,N] + bias) ----------------
// 128x128 tile, BK=8, 256 threads, 8x8 per thread, fp32.
template<bool RELU, bool HASBIAS>
__global__ __launch_bounds__(256) void gemm_kernel(
    const float* __restrict__ A, const float* __restrict__ B,
    const float* __restrict__ bias, float* __restrict__ C,
    int M, int Ncols, int K) {
  constexpr int BM = 128, BN = 128, BK = 8, TM = 8, TN = 8;
  __shared__ float As[BK][BM + 4];
  __shared__ float Bs[BK][BN];
  const int tid = threadIdx.x;
  const int bm = blockIdx.x * BM;
  const int bn = blockIdx.y * BN;
  const int ty = tid / 16, tx = tid % 16;
  const int am = tid >> 3, ak = tid & 7;     // A tile loader coords
  const int bk = tid >> 7, bnl = tid & 127;  // B tile loader coords
  float acc[TM][TN] = {};

  for (int k0 = 0; k0 < K; k0 += BK) {
#pragma unroll
    for (int i = 0; i < 4; i++) {
      int m = am + i * 32;
      int kk = k0 + ak;
      int gr = bm + m;
      float v = 0.f;
      if (gr < M && kk < K) v = A[(long)gr * K + kk];
      As[ak][m] = v;
    }
#pragma unroll
    for (int i = 0; i < 4; i++) {
      int kk = k0 + bk + i * 2;
      float v = 0.f;
      if (kk < K) v = B[(long)kk * Ncols + bn + bnl];
      Bs[bk + i * 2][bnl] = v;
    }
    __syncthreads();
#pragma unroll
    for (int kk = 0; kk < BK; kk++) {
      float a[TM], b[TN];
#pragma unroll
      for (int i = 0; i < TM; i++) a[i] = As[kk][ty * TM + i];
#pragma unroll
      for (int j = 0; j < TN; j++) b[j] = Bs[kk][tx * TN + j];
#pragma unroll
      for (int i = 0; i < TM; i++)
#pragma unroll
        for (int j = 0; j < TN; j++) acc[i][j] += a[i] * b[j];
    }
    __syncthreads();
  }
#pragma unroll
  for (int i = 0; i < TM; i++) {
    int r = bm + ty * TM + i;
    if (r >= M) continue;
#pragma unroll
    for (int j = 0; j < TN; j++) {
      int c = bn + tx * TN + j;
      float v = acc[i][j];
      if (HASBIAS) v += bias[c];
      if (RELU) v = fmaxf(v, 0.f);
      C[(long)r * Ncols + c] = v;
    }
  }
}

// ---------------- small helper kernels ----------------
__global__ void cnt_kernel(const int* __restrict__ dst, float* __restrict__ cnt, int E) {
  int e = blockIdx.x * blockDim.x + threadIdx.x;
  if (e < E) atomicAdd(&cnt[dst[e]], 1.0f);
}

// table[r] = rel_emb[r] . (line @ att_edge)
__global__ void vtable_kernel(const float* __restrict__ line,      // [32,128]
                              const float* __restrict__ att_edge,  // [128]
                              const float* __restrict__ rel_emb,   // [26,32]
                              float* __restrict__ table) {
  __shared__ float ve[32];
  int t = threadIdx.x;  // 64 threads
  if (t < 32) {
    float s = 0.f;
    for (int d = 0; d < 128; d++) s += line[t * 128 + d] * att_edge[d];
    ve[t] = s;
  }
  __syncthreads();
  if (t < 26) {
    float s = 0.f;
    for (int j = 0; j < 32; j++) s += rel_emb[t * 32 + j] * ve[j];
    table[t] = s;
  }
}

// per-node dot products with attention vectors (one wave per node)
__global__ void sdots_kernel(const float* __restrict__ hp,
                             const float* __restrict__ att_src,
                             const float* __restrict__ att_dst,
                             float* __restrict__ ssrc, float* __restrict__ sdst, int n) {
  int wave = (blockIdx.x * blockDim.x + threadIdx.x) >> 6;
  int lane = threadIdx.x & 63;
  if (wave >= n) return;
  const float* row = hp + (long)wave * DD;
  float v0 = row[lane], v1 = row[lane + 64];
  float a = v0 * att_src[lane] + v1 * att_src[lane + 64];
  float b = v0 * att_dst[lane] + v1 * att_dst[lane + 64];
#pragma unroll
  for (int off = 32; off; off >>= 1) {
    a += __shfl_xor(a, off);
    b += __shfl_xor(b, off);
  }
  if (lane == 0) { ssrc[wave] = a; sdst[wave] = b; }
}

__global__ void edgeA_kernel(const int* __restrict__ src, const int* __restrict__ dst,
                             const int* __restrict__ attr, const float* __restrict__ table,
                             const float* __restrict__ ssrc, const float* __restrict__ sdst,
                             float* __restrict__ exbuf, float* __restrict__ den,
                             float* __restrict__ esum, int E) {
  int e = blockIdx.x * blockDim.x + threadIdx.x;
  if (e >= E) return;
  int s = src[e], d = dst[e];
  float t = table[attr[e]];
  float l = ssrc[s] + sdst[d] + t;
  l = (l > 0.f) ? l : NEG_SLOPE * l;
  float ex = expf(l);
  exbuf[e] = ex;
  atomicAdd(&den[d], ex);
  atomicAdd(&esum[d], t);
}

__global__ void nodeloop_kernel(const float* __restrict__ ssrc, const float* __restrict__ sdst,
                                const float* __restrict__ esum, const float* __restrict__ cnt,
                                float* __restrict__ exloop, float* __restrict__ den, int n) {
  int i = blockIdx.x * blockDim.x + threadIdx.x;
  if (i >= n) return;
  float t = esum[i] / fmaxf(cnt[i], 1.0f);
  float l = ssrc[i] + sdst[i] + t;
  l = (l > 0.f) ? l : NEG_SLOPE * l;
  float ex = expf(l);
  exloop[i] = ex;
  den[i] += ex;  // single writer per i; edge atomics finished (separate kernel)
}

// weighted scatter-add: agg[dst] += alpha * hp[src]   (128 threads per edge)
__global__ void edgeB_kernel(const int* __restrict__ src, const int* __restrict__ dst,
                             const float* __restrict__ exbuf, const float* __restrict__ den,
                             const float* __restrict__ hp, float* __restrict__ agg, int E) {
  long tid = (long)blockIdx.x * blockDim.x + threadIdx.x;
  int e = (int)(tid >> 7), c = (int)(tid & 127);
  if (e >= E) return;
  int d = dst[e];
  float alpha = exbuf[e] / (den[d] + 1e-16f);
  atomicAdd(&agg[(long)d * DD + c], alpha * hp[(long)src[e] * DD + c]);
}

__global__ void finish_kernel(const float* __restrict__ agg, const float* __restrict__ hp,
                              const float* __restrict__ exloop, const float* __restrict__ den,
                              const float* __restrict__ bias, float* __restrict__ hout, int n) {
  long tid = (long)blockIdx.x * blockDim.x + threadIdx.x;
  int i = (int)(tid >> 7), c = (int)(tid & 127);
  if (i >= n) return;
  float alpha = exloop[i] / (den[i] + 1e-16f);
  float v = agg[(long)i * DD + c] + alpha * hp[(long)i * DD + c] + bias[c];
  hout[(long)i * DD + c] = fmaxf(v, 0.f);
}

__global__ void pool_kernel(const float* __restrict__ h, float* __restrict__ g, int n) {
  __shared__ float sh[128];
  int tid = threadIdx.x;
  int c = tid & 127, half = tid >> 7;
  float s = 0.f;
  for (int r = blockIdx.x * 2 + half; r < n; r += gridDim.x * 2)
    s += h[(long)r * DD + c];
  if (half == 0) sh[c] = s;
  __syncthreads();
  if (half == 1) atomicAdd(&g[c], sh[c] + s);
}

__global__ void readout_kernel(const float* __restrict__ g, const float* __restrict__ Wr1,
                               const float* __restrict__ br1, const float* __restrict__ Wr2,
                               const float* __restrict__ br2, float* __restrict__ out,
                               float inv_n) {
  __shared__ float gl[128];
  __shared__ float m[64];
  int t = threadIdx.x;  // 64 threads
  gl[t] = g[t] * inv_n;
  gl[t + 64] = g[t + 64] * inv_n;
  __syncthreads();
  {
    float acc = br1[t];
    for (int c = 0; c < 128; c++) acc += gl[c] * Wr1[c * 64 + t];
    m[t] = fmaxf(acc, 0.f);
  }
  __syncthreads();
  if (t < 32) {
    float acc = br2[t];
    for (int j = 0; j < 64; j++) acc += m[j] * Wr2[j * 32 + t];
    out[t] = acc;
  }
}

// ---------------- launch ----------------
extern "C" void kernel_launch(void* const* d_in, const int* in_sizes, int n_in,
                              void* d_out, int out_size, void* d_ws, size_t ws_size,
                              hipStream_t stream) {
  const float* x     = (const float*)d_in[0];
  const int*   ei    = (const int*)d_in[1];
  const int*   eattr = (const int*)d_in[2];
  const float* W1 = (const float*)d_in[3];
  const float* b1 = (const float*)d_in[4];
  const float* W2 = (const float*)d_in[5];
  const float* b2 = (const float*)d_in[6];
  const float* rel_emb = (const float*)d_in[7];
  const float* lin[2]      = {(const float*)d_in[8],  (const float*)d_in[14]};
  const float* att_src[2]  = {(const float*)d_in[9],  (const float*)d_in[15]};
  const float* att_dst[2]  = {(const float*)d_in[10], (const float*)d_in[16]};
  const float* att_edge[2] = {(const float*)d_in[11], (const float*)d_in[17]};
  const float* line[2]     = {(const float*)d_in[12], (const float*)d_in[18]};
  const float* bias[2]     = {(const float*)d_in[13], (const float*)d_in[19]};
  const float* Wr1 = (const float*)d_in[20];
  const float* br1 = (const float*)d_in[21];
  const float* Wr2 = (const float*)d_in[22];
  const float* br2 = (const float*)d_in[23];
  float* out = (float*)d_out;

  const int* srcv = ei;
  const int* dstv = ei + EE;

  float* ws = (float*)d_ws;
  float* hp  = ws;                           // N*128
  float* agg = ws + (size_t)NN * DD;         // N*128   (hp..agg aliases encoder mid)
  float* mid = ws;                           // N*256 (encoder intermediate)
  float* hA  = ws + 2 * (size_t)NN * DD;     // N*128
  float* hB  = ws + 3 * (size_t)NN * DD;     // N*128
  float* ssrc = ws + 4 * (size_t)NN * DD;    // N
  float* sdst = ssrc + NN;
  float* den  = sdst + NN;
  float* esum = den + NN;                    // den+esum contiguous (single memset)
  float* exloop = esum + NN;
  float* cnt  = exloop + NN;
  float* exbuf = cnt + NN;                   // E
  float* table = exbuf + EE;                 // 32
  float* g     = table + 32;                 // 128

  dim3 blk(256);

  hipMemsetAsync(cnt, 0, NN * sizeof(float), stream);
  hipMemsetAsync(g, 0, 128 * sizeof(float), stream);

  // encoder MLP
  gemm_kernel<true, true><<<dim3(391, 2), blk, 0, stream>>>(x, W1, b1, mid, NN, 256, DINK);
  gemm_kernel<false, true><<<dim3(391, 1), blk, 0, stream>>>(mid, W2, b2, hA, NN, 128, 256);
  cnt_kernel<<<dim3((EE + 255) / 256), blk, 0, stream>>>(dstv, cnt, EE);

  const float* hin = hA;
  float* hout = hB;
  for (int L = 0; L < 2; ++L) {
    hipMemsetAsync(den, 0, 2 * NN * sizeof(float), stream);  // den + esum
    gemm_kernel<false, false><<<dim3(391, 1), blk, 0, stream>>>(hin, lin[L], nullptr, hp, NN, 128, 128);
    hipMemsetAsync(agg, 0, (size_t)NN * DD * sizeof(float), stream);
    vtable_kernel<<<1, 64, 0, stream>>>(line[L], att_edge[L], rel_emb, table);
    sdots_kernel<<<dim3((NN * 64 + 255) / 256), blk, 0, stream>>>(hp, att_src[L], att_dst[L], ssrc, sdst, NN);
    edgeA_kernel<<<dim3((EE + 255) / 256), blk, 0, stream>>>(srcv, dstv, eattr, table, ssrc, sdst, exbuf, den, esum, EE);
    nodeloop_kernel<<<dim3((NN + 255) / 256), blk, 0, stream>>>(ssrc, sdst, esum, cnt, exloop, den, NN);
    edgeB_kernel<<<dim3((int)(((long)EE * DD) / 256)), blk, 0, stream>>>(srcv, dstv, exbuf, den, hp, agg, EE);
    finish_kernel<<<dim3((NN * DD) / 256), blk, 0, stream>>>(agg, hp, exloop, den, bias[L], hout, NN);
    const float* t = hin; hin = hout; hout = (float*)t;
  }

  pool_kernel<<<dim3(256), blk, 0, stream>>>(hin, g, NN);
  readout_kernel<<<1, 64, 0, stream>>>(g, Wr1, br1, Wr2, br2, out, 1.0f / NN);
}

// Round 3
// 996.396 us; speedup vs baseline: 1.2159x; 1.2159x over previous
//
#include <hip/hip_runtime.h>
#include <hip/hip_bf16.h>

#define NN   50000
#define EE   600000
#define DINK 518
#define KP1  576          // padded K for encoder GEMM1 (9*64)
#define MP   50048        // padded rows (391*128)
#define DD   128
#define NEG_SLOPE 0.2f

typedef short bf16x8 __attribute__((ext_vector_type(8)));
typedef float f32x4 __attribute__((ext_vector_type(4)));

typedef const __attribute__((address_space(1))) void* gp1_t;
typedef __attribute__((address_space(3))) void* lp3_t;

__device__ __forceinline__ void load_lds16(const void* g, void* l) {
  __builtin_amdgcn_global_load_lds((gp1_t)g, (lp3_t)l, 16, 0, 0);
}

__device__ __forceinline__ unsigned short f2bf(float f) {
  union { float f; unsigned u; } q; q.f = f;
  unsigned u = q.u + 0x7FFFu + ((q.u >> 16) & 1u);   // RNE
  return (unsigned short)(u >> 16);
}

// ---------------- bf16 MFMA GEMM:  C = act(A @ BT^T + bias) ----------------
// A:[Mpad][K] bf16 row-major; BT:[Ncols][K] bf16 (weights pre-transposed).
// 128x128 tile, BK=64, 256 threads (4 waves, each 64x64 = 4x4 frags of 16x16x32).
template<bool OUT_BF16, bool RELU>
__global__ __launch_bounds__(256) void gemm_mfma(
    const unsigned short* __restrict__ A, const unsigned short* __restrict__ BT,
    const float* __restrict__ bias, void* __restrict__ Cout,
    int M, int Ncols, int K) {
  __shared__ short As[128][64];
  __shared__ short Bs[128][64];
  const int tid = threadIdx.x;
  const int lane = tid & 63;
  const int wid = tid >> 6;
  const int wr = wid >> 1, wc = wid & 1;
  const int bm = blockIdx.x * 128;
  const int bn = blockIdx.y * 128;
  const int ar = tid >> 3;          // 0..31 (row within 32-row group)
  const int ac = (tid & 7) * 8;     // k-element offset (16B chunk)

  f32x4 acc[4][4] = {};

  for (int k0 = 0; k0 < K; k0 += 64) {
#pragma unroll
    for (int i = 0; i < 4; i++)
      load_lds16(A + (size_t)(bm + ar + i * 32) * K + k0 + ac, &As[ar + i * 32][ac]);
#pragma unroll
    for (int i = 0; i < 4; i++)
      load_lds16(BT + (size_t)(bn + ar + i * 32) * K + k0 + ac, &Bs[ar + i * 32][ac]);
    __syncthreads();   // compiler drains vmcnt before barrier
#pragma unroll
    for (int ks = 0; ks < 2; ks++) {
      bf16x8 af[4], bfm[4];
#pragma unroll
      for (int f = 0; f < 4; f++)
        af[f] = *(const bf16x8*)&As[wr * 64 + f * 16 + (lane & 15)][ks * 32 + (lane >> 4) * 8];
#pragma unroll
      for (int f = 0; f < 4; f++)
        bfm[f] = *(const bf16x8*)&Bs[wc * 64 + f * 16 + (lane & 15)][ks * 32 + (lane >> 4) * 8];
#pragma unroll
      for (int i = 0; i < 4; i++)
#pragma unroll
        for (int j = 0; j < 4; j++)
          acc[i][j] = __builtin_amdgcn_mfma_f32_16x16x32_bf16(af[i], bfm[j], acc[i][j], 0, 0, 0);
    }
    __syncthreads();
  }

  // C/D layout (m89/m91): col = lane&15, row = (lane>>4)*4 + reg
  const int col0 = bn + wc * 64 + (lane & 15);
  const int row0 = bm + wr * 64 + (lane >> 4) * 4;
#pragma unroll
  for (int i = 0; i < 4; i++) {
#pragma unroll
    for (int jf = 0; jf < 4; jf++) {
      int col = col0 + jf * 16;
      float bv = bias[col];
#pragma unroll
      for (int j = 0; j < 4; j++) {
        int row = row0 + i * 16 + j;
        if (row < M) {
          float v = acc[i][jf][j] + bv;
          if (RELU) v = fmaxf(v, 0.f);
          if (OUT_BF16)
            ((unsigned short*)Cout)[(size_t)row * Ncols + col] = f2bf(v);
          else
            ((float*)Cout)[(size_t)row * Ncols + col] = v;
        }
      }
    }
  }
}

// x fp32 [NN][518] -> xb bf16 [MP][576] (pad already zeroed by memset)
__global__ void convert_x_kernel(const float* __restrict__ x, unsigned short* __restrict__ xb) {
  int t = blockIdx.x * blockDim.x + threadIdx.x;
  if (t >= NN * 260) return;
  int r = t / 260, c = (t % 260) * 2;
  unsigned int o = 0;
  if (c + 1 < DINK) {
    float2 v = *(const float2*)&x[(size_t)r * DINK + c];
    o = (unsigned)f2bf(v.x) | ((unsigned)f2bf(v.y) << 16);
  } else if (c < DINK) {
    o = (unsigned)f2bf(x[(size_t)r * DINK + c]);
  }
  *(unsigned int*)&xb[(size_t)r * KP1 + c] = o;
}

// W [K][Ncols] fp32 -> WT [Ncols][Kpad] bf16 (zero-pad k>=K)
__global__ void convT_kernel(const float* __restrict__ W, unsigned short* __restrict__ WT,
                             int K, int Ncols, int Kpad) {
  int t = blockIdx.x * blockDim.x + threadIdx.x;
  if (t >= Ncols * Kpad) return;
  int n = t / Kpad, k = t % Kpad;
  float v = (k < K) ? W[(size_t)k * Ncols + n] : 0.f;
  WT[(size_t)n * Kpad + k] = f2bf(v);
}

// ---------------- fp32 GEMM (layer lin transforms) ----------------
template<bool RELU, bool HASBIAS>
__global__ __launch_bounds__(256) void gemm_kernel(
    const float* __restrict__ A, const float* __restrict__ B,
    const float* __restrict__ bias, float* __restrict__ C,
    int M, int Ncols, int K) {
  constexpr int BM = 128, BN = 128, BK = 8, TM = 8, TN = 8;
  __shared__ float Asm[BK][BM + 4];
  __shared__ float Bsm[BK][BN];
  const int tid = threadIdx.x;
  const int bm = blockIdx.x * BM;
  const int bn = blockIdx.y * BN;
  const int ty = tid / 16, tx = tid % 16;
  const int am = tid >> 3, ak = tid & 7;
  const int bk = tid >> 7, bnl = tid & 127;
  float acc[TM][TN] = {};

  for (int k0 = 0; k0 < K; k0 += BK) {
#pragma unroll
    for (int i = 0; i < 4; i++) {
      int m = am + i * 32;
      int kk = k0 + ak;
      int gr = bm + m;
      float v = 0.f;
      if (gr < M && kk < K) v = A[(long)gr * K + kk];
      Asm[ak][m] = v;
    }
#pragma unroll
    for (int i = 0; i < 4; i++) {
      int kk = k0 + bk + i * 2;
      float v = 0.f;
      if (kk < K) v = B[(long)kk * Ncols + bn + bnl];
      Bsm[bk + i * 2][bnl] = v;
    }
    __syncthreads();
#pragma unroll
    for (int kk = 0; kk < BK; kk++) {
      float a[TM], b[TN];
#pragma unroll
      for (int i = 0; i < TM; i++) a[i] = Asm[kk][ty * TM + i];
#pragma unroll
      for (int j = 0; j < TN; j++) b[j] = Bsm[kk][tx * TN + j];
#pragma unroll
      for (int i = 0; i < TM; i++)
#pragma unroll
        for (int j = 0; j < TN; j++) acc[i][j] += a[i] * b[j];
    }
    __syncthreads();
  }
#pragma unroll
  for (int i = 0; i < TM; i++) {
    int r = bm + ty * TM + i;
    if (r >= M) continue;
#pragma unroll
    for (int j = 0; j < TN; j++) {
      int c = bn + tx * TN + j;
      float v = acc[i][j];
      if (HASBIAS) v += bias[c];
      if (RELU) v = fmaxf(v, 0.f);
      C[(long)r * Ncols + c] = v;
    }
  }
}

// ---------------- small helper kernels ----------------
__global__ void cnt_kernel(const int* __restrict__ dst, float* __restrict__ cnt, int E) {
  int e = blockIdx.x * blockDim.x + threadIdx.x;
  if (e < E) atomicAdd(&cnt[dst[e]], 1.0f);
}

// table[r] = rel_emb[r] . (line @ att_edge)
__global__ void vtable_kernel(const float* __restrict__ line,
                              const float* __restrict__ att_edge,
                              const float* __restrict__ rel_emb,
                              float* __restrict__ table) {
  __shared__ float ve[32];
  int t = threadIdx.x;  // 64 threads
  if (t < 32) {
    float s = 0.f;
    for (int d = 0; d < 128; d++) s += line[t * 128 + d] * att_edge[d];
    ve[t] = s;
  }
  __syncthreads();
  if (t < 26) {
    float s = 0.f;
    for (int j = 0; j < 32; j++) s += rel_emb[t * 32 + j] * ve[j];
    table[t] = s;
  }
}

__global__ void sdots_kernel(const float* __restrict__ hp,
                             const float* __restrict__ att_src,
                             const float* __restrict__ att_dst,
                             float* __restrict__ ssrc, float* __restrict__ sdst, int n) {
  int wave = (blockIdx.x * blockDim.x + threadIdx.x) >> 6;
  int lane = threadIdx.x & 63;
  if (wave >= n) return;
  const float* row = hp + (long)wave * DD;
  float v0 = row[lane], v1 = row[lane + 64];
  float a = v0 * att_src[lane] + v1 * att_src[lane + 64];
  float b = v0 * att_dst[lane] + v1 * att_dst[lane + 64];
#pragma unroll
  for (int off = 32; off; off >>= 1) {
    a += __shfl_xor(a, off);
    b += __shfl_xor(b, off);
  }
  if (lane == 0) { ssrc[wave] = a; sdst[wave] = b; }
}

__global__ void edgeA_kernel(const int* __restrict__ src, const int* __restrict__ dst,
                             const int* __restrict__ attr, const float* __restrict__ table,
                             const float* __restrict__ ssrc, const float* __restrict__ sdst,
                             float* __restrict__ exbuf, float* __restrict__ den,
                             float* __restrict__ esum, int E) {
  int e = blockIdx.x * blockDim.x + threadIdx.x;
  if (e >= E) return;
  int s = src[e], d = dst[e];
  float t = table[attr[e]];
  float l = ssrc[s] + sdst[d] + t;
  l = (l > 0.f) ? l : NEG_SLOPE * l;
  float ex = expf(l);
  exbuf[e] = ex;
  atomicAdd(&den[d], ex);
  atomicAdd(&esum[d], t);
}

__global__ void nodeloop_kernel(const float* __restrict__ ssrc, const float* __restrict__ sdst,
                                const float* __restrict__ esum, const float* __restrict__ cnt,
                                float* __restrict__ exloop, float* __restrict__ den, int n) {
  int i = blockIdx.x * blockDim.x + threadIdx.x;
  if (i >= n) return;
  float t = esum[i] / fmaxf(cnt[i], 1.0f);
  float l = ssrc[i] + sdst[i] + t;
  l = (l > 0.f) ? l : NEG_SLOPE * l;
  float ex = expf(l);
  exloop[i] = ex;
  den[i] += ex;
}

__global__ void edgeB_kernel(const int* __restrict__ src, const int* __restrict__ dst,
                             const float* __restrict__ exbuf, const float* __restrict__ den,
                             const float* __restrict__ hp, float* __restrict__ agg, int E) {
  long tid = (long)blockIdx.x * blockDim.x + threadIdx.x;
  int e = (int)(tid >> 7), c = (int)(tid & 127);
  if (e >= E) return;
  int d = dst[e];
  float alpha = exbuf[e] / (den[d] + 1e-16f);
  atomicAdd(&agg[(long)d * DD + c], alpha * hp[(long)src[e] * DD + c]);
}

__global__ void finish_kernel(const float* __restrict__ agg, const float* __restrict__ hp,
                              const float* __restrict__ exloop, const float* __restrict__ den,
                              const float* __restrict__ bias, float* __restrict__ hout, int n) {
  long tid = (long)blockIdx.x * blockDim.x + threadIdx.x;
  int i = (int)(tid >> 7), c = (int)(tid & 127);
  if (i >= n) return;
  float alpha = exloop[i] / (den[i] + 1e-16f);
  float v = agg[(long)i * DD + c] + alpha * hp[(long)i * DD + c] + bias[c];
  hout[(long)i * DD + c] = fmaxf(v, 0.f);
}

__global__ void pool_kernel(const float* __restrict__ h, float* __restrict__ g, int n) {
  __shared__ float sh[128];
  int tid = threadIdx.x;
  int c = tid & 127, half = tid >> 7;
  float s = 0.f;
  for (int r = blockIdx.x * 2 + half; r < n; r += gridDim.x * 2)
    s += h[(long)r * DD + c];
  if (half == 0) sh[c] = s;
  __syncthreads();
  if (half == 1) atomicAdd(&g[c], sh[c] + s);
}

__global__ void readout_kernel(const float* __restrict__ g, const float* __restrict__ Wr1,
                               const float* __restrict__ br1, const float* __restrict__ Wr2,
                               const float* __restrict__ br2, float* __restrict__ out,
                               float inv_n) {
  __shared__ float gl[128];
  __shared__ float m[64];
  int t = threadIdx.x;  // 64 threads
  gl[t] = g[t] * inv_n;
  gl[t + 64] = g[t + 64] * inv_n;
  __syncthreads();
  {
    float acc = br1[t];
    for (int c = 0; c < 128; c++) acc += gl[c] * Wr1[c * 64 + t];
    m[t] = fmaxf(acc, 0.f);
  }
  __syncthreads();
  if (t < 32) {
    float acc = br2[t];
    for (int j = 0; j < 64; j++) acc += m[j] * Wr2[j * 32 + t];
    out[t] = acc;
  }
}

// ---------------- launch ----------------
extern "C" void kernel_launch(void* const* d_in, const int* in_sizes, int n_in,
                              void* d_out, int out_size, void* d_ws, size_t ws_size,
                              hipStream_t stream) {
  const float* x     = (const float*)d_in[0];
  const int*   ei    = (const int*)d_in[1];
  const int*   eattr = (const int*)d_in[2];
  const float* W1 = (const float*)d_in[3];
  const float* b1 = (const float*)d_in[4];
  const float* W2 = (const float*)d_in[5];
  const float* b2 = (const float*)d_in[6];
  const float* rel_emb = (const float*)d_in[7];
  const float* lin[2]      = {(const float*)d_in[8],  (const float*)d_in[14]};
  const float* att_src[2]  = {(const float*)d_in[9],  (const float*)d_in[15]};
  const float* att_dst[2]  = {(const float*)d_in[10], (const float*)d_in[16]};
  const float* att_edge[2] = {(const float*)d_in[11], (const float*)d_in[17]};
  const float* line[2]     = {(const float*)d_in[12], (const float*)d_in[18]};
  const float* bias[2]     = {(const float*)d_in[13], (const float*)d_in[19]};
  const float* Wr1 = (const float*)d_in[20];
  const float* br1 = (const float*)d_in[21];
  const float* Wr2 = (const float*)d_in[22];
  const float* br2 = (const float*)d_in[23];
  float* out = (float*)d_out;

  const int* srcv = ei;
  const int* dstv = ei + EE;

  // Workspace overlay (byte offsets; encoder buffers alias layer buffers):
  //  [0 .. 57.66M)   xb bf16 [MP][576]   (dead after GEMM1)
  //  [0 .. 25.6M)    hA fp32             (written by GEMM2, after xb dead)
  //  [25.6M..51.2M)  hp fp32             (layer phase only)
  //  [51.2M..76.8M)  hB fp32             (layer phase only)
  //  [57.66M..83.3M) mid bf16 [MP][256]  (dead after GEMM2)
  //  [76.8M..102.4M) agg fp32            (layer phase only; first write = memset)
  //  [84.0M..84.66M) W1T/W2T bf16        (encoder only, inside agg region)
  //  [102.4M..106M)  small + exbuf
  char* wsb = (char*)d_ws;
  unsigned short* xb  = (unsigned short*)(wsb + 0);
  float* hA  = (float*)(wsb + 0);
  float* hp  = (float*)(wsb + 25600000);
  float* hB  = (float*)(wsb + 51200000);
  unsigned short* mid = (unsigned short*)(wsb + 57655296);
  float* agg = (float*)(wsb + 76800000);
  unsigned short* W1T = (unsigned short*)(wsb + 84000000);
  unsigned short* W2T = (unsigned short*)(wsb + 84300000);
  float* ssrc   = (float*)(wsb + 102400000);
  float* sdst   = (float*)(wsb + 102600000);
  float* den    = (float*)(wsb + 102800000);
  float* esum   = (float*)(wsb + 103000000);
  float* exloop = (float*)(wsb + 103200000);
  float* cnt    = (float*)(wsb + 103400000);
  float* exbuf  = (float*)(wsb + 103600000);
  float* table  = (float*)(wsb + 106000000);
  float* g      = (float*)(wsb + 106000128);

  dim3 blk(256);

  hipMemsetAsync(xb, 0, (size_t)MP * KP1 * 2, stream);  // zeros k-pad cols + pad rows
  hipMemsetAsync(cnt, 0, NN * sizeof(float), stream);
  hipMemsetAsync(g, 0, 128 * sizeof(float), stream);

  // encoder: convert + bf16 MFMA GEMMs
  convert_x_kernel<<<dim3((NN * 260 + 255) / 256), blk, 0, stream>>>(x, xb);
  convT_kernel<<<dim3((256 * KP1 + 255) / 256), blk, 0, stream>>>(W1, W1T, DINK, 256, KP1);
  convT_kernel<<<dim3((128 * 256 + 255) / 256), blk, 0, stream>>>(W2, W2T, 256, 128, 256);
  gemm_mfma<true, true><<<dim3(391, 2), blk, 0, stream>>>(xb, W1T, b1, mid, NN, 256, KP1);
  gemm_mfma<false, false><<<dim3(391, 1), blk, 0, stream>>>(mid, W2T, b2, hA, NN, 128, 256);
  cnt_kernel<<<dim3((EE + 255) / 256), blk, 0, stream>>>(dstv, cnt, EE);

  const float* hin = hA;
  float* hout = hB;
  for (int L = 0; L < 2; ++L) {
    hipMemsetAsync(den, 0, 2 * NN * sizeof(float), stream);  // den + esum
    gemm_kernel<false, false><<<dim3(391, 1), blk, 0, stream>>>(hin, lin[L], nullptr, hp, NN, 128, 128);
    hipMemsetAsync(agg, 0, (size_t)NN * DD * sizeof(float), stream);
    vtable_kernel<<<1, 64, 0, stream>>>(line[L], att_edge[L], rel_emb, table);
    sdots_kernel<<<dim3((NN * 64 + 255) / 256), blk, 0, stream>>>(hp, att_src[L], att_dst[L], ssrc, sdst, NN);
    edgeA_kernel<<<dim3((EE + 255) / 256), blk, 0, stream>>>(srcv, dstv, eattr, table, ssrc, sdst, exbuf, den, esum, EE);
    nodeloop_kernel<<<dim3((NN + 255) / 256), blk, 0, stream>>>(ssrc, sdst, esum, cnt, exloop, den, NN);
    edgeB_kernel<<<dim3((int)(((long)EE * DD) / 256)), blk, 0, stream>>>(srcv, dstv, exbuf, den, hp, agg, EE);
    finish_kernel<<<dim3((NN * DD) / 256), blk, 0, stream>>>(agg, hp, exloop, den, bias[L], hout, NN);
    const float* t = hin; hin = hout; hout = (float*)t;
  }

  pool_kernel<<<dim3(256), blk, 0, stream>>>(hin, g, NN);
  readout_kernel<<<1, 64, 0, stream>>>(g, Wr1, br1, Wr2, br2, out, 1.0f / NN);
}

// Round 4
// 493.743 us; speedup vs baseline: 2.4538x; 2.0180x over previous
//
#include <hip/hip_runtime.h>
#include <hip/hip_bf16.h>

#define NN   50000
#define EE   600000
#define DINK 518
#define KP1  576          // padded K for encoder GEMM1 (9*64)
#define MP   50048        // padded rows (391*128)
#define DD   128
#define NEG_SLOPE 0.2f
#define CAP  256          // per-wave LDS exp stash (max in-degree fast path)

typedef short bf16x8 __attribute__((ext_vector_type(8)));
typedef float f32x4 __attribute__((ext_vector_type(4)));

typedef const __attribute__((address_space(1))) void* gp1_t;
typedef __attribute__((address_space(3))) void* lp3_t;

__device__ __forceinline__ void load_lds16(const void* g, void* l) {
  __builtin_amdgcn_global_load_lds((gp1_t)g, (lp3_t)l, 16, 0, 0);
}

__device__ __forceinline__ unsigned short f2bf(float f) {
  union { float f; unsigned u; } q; q.f = f;
  unsigned u = q.u + 0x7FFFu + ((q.u >> 16) & 1u);   // RNE
  return (unsigned short)(u >> 16);
}

// ---------------- bf16 MFMA GEMM:  C = act(A @ BT^T + bias) ----------------
template<bool OUT_BF16, bool RELU>
__global__ __launch_bounds__(256) void gemm_mfma(
    const unsigned short* __restrict__ A, const unsigned short* __restrict__ BT,
    const float* __restrict__ bias, void* __restrict__ Cout,
    int M, int Ncols, int K) {
  __shared__ short As[128][64];
  __shared__ short Bs[128][64];
  const int tid = threadIdx.x;
  const int lane = tid & 63;
  const int wid = tid >> 6;
  const int wr = wid >> 1, wc = wid & 1;
  const int bm = blockIdx.x * 128;
  const int bn = blockIdx.y * 128;
  const int ar = tid >> 3;
  const int ac = (tid & 7) * 8;

  f32x4 acc[4][4] = {};

  for (int k0 = 0; k0 < K; k0 += 64) {
#pragma unroll
    for (int i = 0; i < 4; i++)
      load_lds16(A + (size_t)(bm + ar + i * 32) * K + k0 + ac, &As[ar + i * 32][ac]);
#pragma unroll
    for (int i = 0; i < 4; i++)
      load_lds16(BT + (size_t)(bn + ar + i * 32) * K + k0 + ac, &Bs[ar + i * 32][ac]);
    __syncthreads();
#pragma unroll
    for (int ks = 0; ks < 2; ks++) {
      bf16x8 af[4], bfm[4];
#pragma unroll
      for (int f = 0; f < 4; f++)
        af[f] = *(const bf16x8*)&As[wr * 64 + f * 16 + (lane & 15)][ks * 32 + (lane >> 4) * 8];
#pragma unroll
      for (int f = 0; f < 4; f++)
        bfm[f] = *(const bf16x8*)&Bs[wc * 64 + f * 16 + (lane & 15)][ks * 32 + (lane >> 4) * 8];
#pragma unroll
      for (int i = 0; i < 4; i++)
#pragma unroll
        for (int j = 0; j < 4; j++)
          acc[i][j] = __builtin_amdgcn_mfma_f32_16x16x32_bf16(af[i], bfm[j], acc[i][j], 0, 0, 0);
    }
    __syncthreads();
  }

  const int col0 = bn + wc * 64 + (lane & 15);
  const int row0 = bm + wr * 64 + (lane >> 4) * 4;
#pragma unroll
  for (int i = 0; i < 4; i++) {
#pragma unroll
    for (int jf = 0; jf < 4; jf++) {
      int col = col0 + jf * 16;
      float bv = bias[col];
#pragma unroll
      for (int j = 0; j < 4; j++) {
        int row = row0 + i * 16 + j;
        if (row < M) {
          float v = acc[i][jf][j] + bv;
          if (RELU) v = fmaxf(v, 0.f);
          if (OUT_BF16)
            ((unsigned short*)Cout)[(size_t)row * Ncols + col] = f2bf(v);
          else
            ((float*)Cout)[(size_t)row * Ncols + col] = v;
        }
      }
    }
  }
}

// x fp32 [NN][518] -> xb bf16 [NN][576] (k-pad written as zeros; pad ROWS left
// stale: MFMA is row-independent so they only affect never-read pad outputs)
__global__ void convert_x_kernel(const float* __restrict__ x, unsigned short* __restrict__ xb) {
  int t = blockIdx.x * blockDim.x + threadIdx.x;
  if (t >= NN * 288) return;
  int r = t / 288, c = (t % 288) * 2;
  unsigned int o = 0;
  if (c + 1 < DINK) {
    float2 v = *(const float2*)&x[(size_t)r * DINK + c];
    o = (unsigned)f2bf(v.x) | ((unsigned)f2bf(v.y) << 16);
  } else if (c < DINK) {
    o = (unsigned)f2bf(x[(size_t)r * DINK + c]);
  }
  *(unsigned int*)&xb[(size_t)r * KP1 + c] = o;
}

// W [K][Ncols] fp32 -> WT [Ncols][Kpad] bf16 (zero-pad k>=K)
__global__ void convT_kernel(const float* __restrict__ W, unsigned short* __restrict__ WT,
                             int K, int Ncols, int Kpad) {
  int t = blockIdx.x * blockDim.x + threadIdx.x;
  if (t >= Ncols * Kpad) return;
  int n = t / Kpad, k = t % Kpad;
  float v = (k < K) ? W[(size_t)k * Ncols + n] : 0.f;
  WT[(size_t)n * Kpad + k] = f2bf(v);
}

// ---------------- fp32 GEMM (layer lin transforms) ----------------
template<bool RELU, bool HASBIAS>
__global__ __launch_bounds__(256) void gemm_kernel(
    const float* __restrict__ A, const float* __restrict__ B,
    const float* __restrict__ bias, float* __restrict__ C,
    int M, int Ncols, int K) {
  constexpr int BM = 128, BN = 128, BK = 8, TM = 8, TN = 8;
  __shared__ float Asm[BK][BM + 4];
  __shared__ float Bsm[BK][BN];
  const int tid = threadIdx.x;
  const int bm = blockIdx.x * BM;
  const int bn = blockIdx.y * BN;
  const int ty = tid / 16, tx = tid % 16;
  const int am = tid >> 3, ak = tid & 7;
  const int bk = tid >> 7, bnl = tid & 127;
  float acc[TM][TN] = {};

  for (int k0 = 0; k0 < K; k0 += BK) {
#pragma unroll
    for (int i = 0; i < 4; i++) {
      int m = am + i * 32;
      int kk = k0 + ak;
      int gr = bm + m;
      float v = 0.f;
      if (gr < M && kk < K) v = A[(long)gr * K + kk];
      Asm[ak][m] = v;
    }
#pragma unroll
    for (int i = 0; i < 4; i++) {
      int kk = k0 + bk + i * 2;
      float v = 0.f;
      if (kk < K) v = B[(long)kk * Ncols + bn + bnl];
      Bsm[bk + i * 2][bnl] = v;
    }
    __syncthreads();
#pragma unroll
    for (int kk = 0; kk < BK; kk++) {
      float a[TM], b[TN];
#pragma unroll
      for (int i = 0; i < TM; i++) a[i] = Asm[kk][ty * TM + i];
#pragma unroll
      for (int j = 0; j < TN; j++) b[j] = Bsm[kk][tx * TN + j];
#pragma unroll
      for (int i = 0; i < TM; i++)
#pragma unroll
        for (int j = 0; j < TN; j++) acc[i][j] += a[i] * b[j];
    }
    __syncthreads();
  }
#pragma unroll
  for (int i = 0; i < TM; i++) {
    int r = bm + ty * TM + i;
    if (r >= M) continue;
#pragma unroll
    for (int j = 0; j < TN; j++) {
      int c = bn + tx * TN + j;
      float v = acc[i][j];
      if (HASBIAS) v += bias[c];
      if (RELU) v = fmaxf(v, 0.f);
      C[(long)r * Ncols + c] = v;
    }
  }
}

// ---------------- CSR build (counting sort by dst; reused by both layers) ----
__global__ void cnti_kernel(const int* __restrict__ dst, int* __restrict__ cnti, int E) {
  int e = blockIdx.x * blockDim.x + threadIdx.x;
  if (e < E) atomicAdd(&cnti[dst[e]], 1);
}

// phase 1: per-block sums of cnti
__global__ void partial_kernel(const int* __restrict__ cnti, int* __restrict__ partial, int n) {
  __shared__ int sh[4];
  int i = blockIdx.x * 256 + threadIdx.x;
  int lane = threadIdx.x & 63, wid = threadIdx.x >> 6;
  int v = (i < n) ? cnti[i] : 0;
#pragma unroll
  for (int off = 32; off; off >>= 1) v += __shfl_xor(v, off);
  if (lane == 0) sh[wid] = v;
  __syncthreads();
  if (threadIdx.x == 0) partial[blockIdx.x] = sh[0] + sh[1] + sh[2] + sh[3];
}

// phase 2: exclusive scan of the (<=256) partials, single block
__global__ void scanpartial_kernel(const int* __restrict__ partial, int* __restrict__ poffs,
                                   int* __restrict__ rowptr, int nb) {
  __shared__ int buf[256];
  int t = threadIdx.x;
  int v = (t < nb) ? partial[t] : 0;
  buf[t] = v;
  __syncthreads();
  for (int off = 1; off < 256; off <<= 1) {
    int add = (t >= off) ? buf[t - off] : 0;
    __syncthreads();
    buf[t] += add;
    __syncthreads();
  }
  if (t < nb) poffs[t] = buf[t] - v;   // exclusive
  if (t == 0) rowptr[NN] = EE;
}

// phase 3: per-block scan + global offset -> rowptr, wtr
__global__ void scatter_scan_kernel(const int* __restrict__ cnti, const int* __restrict__ poffs,
                                    int* __restrict__ rowptr, int* __restrict__ wtr, int n) {
  __shared__ int buf[256];
  int t = threadIdx.x;
  int i = blockIdx.x * 256 + t;
  int v = (i < n) ? cnti[i] : 0;
  buf[t] = v;
  __syncthreads();
  for (int off = 1; off < 256; off <<= 1) {
    int add = (t >= off) ? buf[t - off] : 0;
    __syncthreads();
    buf[t] += add;
    __syncthreads();
  }
  if (i < n) {
    int r = poffs[blockIdx.x] + buf[t] - v;
    rowptr[i] = r;
    wtr[i] = r;
  }
}

__global__ void place_kernel(const int* __restrict__ src, const int* __restrict__ dst,
                             const int* __restrict__ attr, int* __restrict__ wtr,
                             int* __restrict__ csrc, int* __restrict__ cattr, int E) {
  int e = blockIdx.x * blockDim.x + threadIdx.x;
  if (e >= E) return;
  int p = atomicAdd(&wtr[dst[e]], 1);
  csrc[p] = src[e];
  cattr[p] = attr[e];
}

// ---------------- GAT helpers ----------------
// table[r] = rel_emb[r] . (line @ att_edge)
__global__ void vtable_kernel(const float* __restrict__ line,
                              const float* __restrict__ att_edge,
                              const float* __restrict__ rel_emb,
                              float* __restrict__ table) {
  __shared__ float ve[32];
  int t = threadIdx.x;  // 64 threads
  if (t < 32) {
    float s = 0.f;
    for (int d = 0; d < 128; d++) s += line[t * 128 + d] * att_edge[d];
    ve[t] = s;
  }
  __syncthreads();
  if (t < 26) {
    float s = 0.f;
    for (int j = 0; j < 32; j++) s += rel_emb[t * 32 + j] * ve[j];
    table[t] = s;
  }
}

__global__ void sdots_kernel(const float* __restrict__ hp,
                             const float* __restrict__ att_src,
                             const float* __restrict__ att_dst,
                             float* __restrict__ ssrc, float* __restrict__ sdst, int n) {
  int wave = (blockIdx.x * blockDim.x + threadIdx.x) >> 6;
  int lane = threadIdx.x & 63;
  if (wave >= n) return;
  const float* row = hp + (long)wave * DD;
  float v0 = row[lane], v1 = row[lane + 64];
  float a = v0 * att_src[lane] + v1 * att_src[lane + 64];
  float b = v0 * att_dst[lane] + v1 * att_dst[lane + 64];
#pragma unroll
  for (int off = 32; off; off >>= 1) {
    a += __shfl_xor(a, off);
    b += __shfl_xor(b, off);
  }
  if (lane == 0) { ssrc[wave] = a; sdst[wave] = b; }
}

// ---------------- fused GAT aggregate: one wave per dst node ----------------
// pass1 (lane-parallel over edges): logits -> exp (stashed in LDS), reduce den/esum
// self-loop folded in-register; pass2: each lane owns 2 cols, gather-accumulate.
__global__ __launch_bounds__(256) void gat_gather_kernel(
    const int* __restrict__ rowptr, const int* __restrict__ csrc,
    const int* __restrict__ cattr, const float* __restrict__ table,
    const float* __restrict__ ssrc, const float* __restrict__ sdst,
    const float* __restrict__ hp, const float* __restrict__ bias,
    float* __restrict__ hout, int n) {
  __shared__ float exs[4][CAP];
  const int wid = threadIdx.x >> 6, lane = threadIdx.x & 63;
  const int node = (blockIdx.x * blockDim.x + threadIdx.x) >> 6;
  if (node >= n) return;
  const int j0 = rowptr[node], j1 = rowptr[node + 1];
  const int deg = j1 - j0;
  const float sd = sdst[node];
  float den = 0.f, esum = 0.f;
  for (int j = j0 + lane; j < j1; j += 64) {
    float t = table[cattr[j]];
    float l = ssrc[csrc[j]] + sd + t;
    l = (l > 0.f) ? l : NEG_SLOPE * l;
    float ex = expf(l);
    int k = j - j0;
    if (k < CAP) exs[wid][k] = ex;
    den += ex; esum += t;
  }
#pragma unroll
  for (int off = 32; off; off >>= 1) {
    den += __shfl_xor(den, off);
    esum += __shfl_xor(esum, off);
  }
  // self-loop (edge vector = mean of incoming -> table-space mean)
  float tl = esum / fmaxf((float)deg, 1.f);
  float ll = ssrc[node] + sd + tl;
  ll = (ll > 0.f) ? ll : NEG_SLOPE * ll;
  float exl = expf(ll);
  den += exl;
  const float inv = 1.f / (den + 1e-16f);
  // pass 2
  const int c = lane * 2;
  float2 acc;
  {
    float2 v = *(const float2*)&hp[(size_t)node * DD + c];
    float a = exl * inv;
    acc.x = a * v.x; acc.y = a * v.y;
  }
  for (int j = j0; j < j1; j++) {
    int k = j - j0;
    float ex;
    if (k < CAP) ex = exs[wid][k];
    else {  // cold fallback, deg > CAP (never for this graph)
      float t = table[cattr[j]];
      float l = ssrc[csrc[j]] + sd + t;
      l = (l > 0.f) ? l : NEG_SLOPE * l;
      ex = expf(l);
    }
    float a = ex * inv;
    float2 v = *(const float2*)&hp[(size_t)csrc[j] * DD + c];
    acc.x += a * v.x; acc.y += a * v.y;
  }
  acc.x = fmaxf(acc.x + bias[c], 0.f);
  acc.y = fmaxf(acc.y + bias[c + 1], 0.f);
  *(float2*)&hout[(size_t)node * DD + c] = acc;
}

__global__ void pool_kernel(const float* __restrict__ h, float* __restrict__ g, int n) {
  __shared__ float sh[128];
  int tid = threadIdx.x;
  int c = tid & 127, half = tid >> 7;
  float s = 0.f;
  for (int r = blockIdx.x * 2 + half; r < n; r += gridDim.x * 2)
    s += h[(long)r * DD + c];
  if (half == 0) sh[c] = s;
  __syncthreads();
  if (half == 1) atomicAdd(&g[c], sh[c] + s);
}

__global__ void readout_kernel(const float* __restrict__ g, const float* __restrict__ Wr1,
                               const float* __restrict__ br1, const float* __restrict__ Wr2,
                               const float* __restrict__ br2, float* __restrict__ out,
                               float inv_n) {
  __shared__ float gl[128];
  __shared__ float m[64];
  int t = threadIdx.x;  // 64 threads
  gl[t] = g[t] * inv_n;
  gl[t + 64] = g[t + 64] * inv_n;
  __syncthreads();
  {
    float acc = br1[t];
    for (int c = 0; c < 128; c++) acc += gl[c] * Wr1[c * 64 + t];
    m[t] = fmaxf(acc, 0.f);
  }
  __syncthreads();
  if (t < 32) {
    float acc = br2[t];
    for (int j = 0; j < 64; j++) acc += m[j] * Wr2[j * 32 + t];
    out[t] = acc;
  }
}

// ---------------- launch ----------------
extern "C" void kernel_launch(void* const* d_in, const int* in_sizes, int n_in,
                              void* d_out, int out_size, void* d_ws, size_t ws_size,
                              hipStream_t stream) {
  const float* x     = (const float*)d_in[0];
  const int*   ei    = (const int*)d_in[1];
  const int*   eattr = (const int*)d_in[2];
  const float* W1 = (const float*)d_in[3];
  const float* b1 = (const float*)d_in[4];
  const float* W2 = (const float*)d_in[5];
  const float* b2 = (const float*)d_in[6];
  const float* rel_emb = (const float*)d_in[7];
  const float* lin[2]      = {(const float*)d_in[8],  (const float*)d_in[14]};
  const float* att_src[2]  = {(const float*)d_in[9],  (const float*)d_in[15]};
  const float* att_dst[2]  = {(const float*)d_in[10], (const float*)d_in[16]};
  const float* att_edge[2] = {(const float*)d_in[11], (const float*)d_in[17]};
  const float* line[2]     = {(const float*)d_in[12], (const float*)d_in[18]};
  const float* bias[2]     = {(const float*)d_in[13], (const float*)d_in[19]};
  const float* Wr1 = (const float*)d_in[20];
  const float* br1 = (const float*)d_in[21];
  const float* Wr2 = (const float*)d_in[22];
  const float* br2 = (const float*)d_in[23];
  float* out = (float*)d_out;

  const int* srcv = ei;
  const int* dstv = ei + EE;

  // Workspace overlay (byte offsets):
  //  [0 .. 57.66M)        xb bf16 [MP][576]   (encoder only; dead after GEMM1)
  //  [0 .. 25.6M)         hA fp32             (GEMM2 output onward)
  //  [25.6M .. 51.2M)     hp fp32             (layer phase; xb dead by then)
  //  [57.66M .. 83.28M)   mid bf16 [MP][256]  (dead after GEMM2) / hB fp32 (layer phase)
  //  [83.3M ..)           W1T, W2T, CSR arrays, small vectors
  char* wsb = (char*)d_ws;
  unsigned short* xb  = (unsigned short*)(wsb + 0);
  float* hA  = (float*)(wsb + 0);
  float* hp  = (float*)(wsb + 25600000);
  unsigned short* mid = (unsigned short*)(wsb + 57655296);
  float* hB  = (float*)(wsb + 57655296);
  unsigned short* W1T = (unsigned short*)(wsb + 83300000);
  unsigned short* W2T = (unsigned short*)(wsb + 83600000);
  int* rowptr  = (int*)(wsb + 83700000);
  int* wtr     = (int*)(wsb + 83900008);
  int* cnti    = (int*)(wsb + 84100008);
  int* csrc    = (int*)(wsb + 84300008);
  int* cattr   = (int*)(wsb + 86700008);
  float* ssrc  = (float*)(wsb + 89100008);
  float* sdst  = (float*)(wsb + 89300008);
  int* partial = (int*)(wsb + 89500008);
  int* poffs   = (int*)(wsb + 89501032);
  float* table = (float*)(wsb + 89502056);
  float* g     = (float*)(wsb + 89502184);

  dim3 blk(256);
  const int NBLK = (NN + 255) / 256;  // 196

  hipMemsetAsync(cnti, 0, NN * sizeof(int), stream);
  hipMemsetAsync(g, 0, 128 * sizeof(float), stream);

  // encoder: convert + bf16 MFMA GEMMs
  convert_x_kernel<<<dim3((NN * 288 + 255) / 256), blk, 0, stream>>>(x, xb);
  convT_kernel<<<dim3((256 * KP1 + 255) / 256), blk, 0, stream>>>(W1, W1T, DINK, 256, KP1);
  convT_kernel<<<dim3((128 * 256 + 255) / 256), blk, 0, stream>>>(W2, W2T, 256, 128, 256);
  gemm_mfma<true, true><<<dim3(391, 2), blk, 0, stream>>>(xb, W1T, b1, mid, NN, 256, KP1);
  gemm_mfma<false, false><<<dim3(391, 1), blk, 0, stream>>>(mid, W2T, b2, hA, NN, 128, 256);

  // CSR build (once; both layers reuse)
  cnti_kernel<<<dim3((EE + 255) / 256), blk, 0, stream>>>(dstv, cnti, EE);
  partial_kernel<<<dim3(NBLK), blk, 0, stream>>>(cnti, partial, NN);
  scanpartial_kernel<<<1, 256, 0, stream>>>(partial, poffs, rowptr, NBLK);
  scatter_scan_kernel<<<dim3(NBLK), blk, 0, stream>>>(cnti, poffs, rowptr, wtr, NN);
  place_kernel<<<dim3((EE + 255) / 256), blk, 0, stream>>>(srcv, dstv, eattr, wtr, csrc, cattr, EE);

  const float* hin = hA;
  float* hout = hB;
  for (int L = 0; L < 2; ++L) {
    gemm_kernel<false, false><<<dim3(391, 1), blk, 0, stream>>>(hin, lin[L], nullptr, hp, NN, 128, 128);
    vtable_kernel<<<1, 64, 0, stream>>>(line[L], att_edge[L], rel_emb, table);
    sdots_kernel<<<dim3((NN * 64 + 255) / 256), blk, 0, stream>>>(hp, att_src[L], att_dst[L], ssrc, sdst, NN);
    gat_gather_kernel<<<dim3((NN * 64 + 255) / 256), blk, 0, stream>>>(
        rowptr, csrc, cattr, table, ssrc, sdst, hp, bias[L], hout, NN);
    const float* t = hin; hin = hout; hout = (float*)t;
  }

  pool_kernel<<<dim3(256), blk, 0, stream>>>(hin, g, NN);
  readout_kernel<<<1, 64, 0, stream>>>(g, Wr1, br1, Wr2, br2, out, 1.0f / NN);
}

// Round 6
// 411.340 us; speedup vs baseline: 2.9454x; 1.2003x over previous
//
#include <hip/hip_runtime.h>
#include <hip/hip_bf16.h>

#define NN   50000
#define EE   600000
#define DINK 518
#define KP1  576          // padded K for encoder GEMM1 (9*64)
#define MP   50048        // padded rows (391*128)
#define DD   128
#define NEG_SLOPE 0.2f
#define CAP  256          // per-wave LDS exp stash (max in-degree fast path)

typedef short bf16x8 __attribute__((ext_vector_type(8)));
typedef float f32x4 __attribute__((ext_vector_type(4)));

typedef const __attribute__((address_space(1))) void* gp1_t;
typedef __attribute__((address_space(3))) void* lp3_t;

__device__ __forceinline__ void load_lds16(const void* g, void* l) {
  __builtin_amdgcn_global_load_lds((gp1_t)g, (lp3_t)l, 16, 0, 0);
}

__device__ __forceinline__ unsigned short f2bf(float f) {
  union { float f; unsigned u; } q; q.f = f;
  unsigned u = q.u + 0x7FFFu + ((q.u >> 16) & 1u);   // RNE
  return (unsigned short)(u >> 16);
}
__device__ __forceinline__ float bflo(unsigned u) {
  union { unsigned u; float f; } q; q.u = u << 16; return q.f;
}
__device__ __forceinline__ float bfhi(unsigned u) {
  union { unsigned u; float f; } q; q.u = u & 0xFFFF0000u; return q.f;
}

// ---------------- bf16 MFMA GEMM:  C = act(A @ BT^T [+ bias]) ----------------
// A:[Mpad][K] bf16 row-major; BT:[Ncols][K] bf16. 128x128 tile, BK=64, 4 waves.
template<bool OUT_BF16, bool RELU, bool HASBIAS>
__global__ __launch_bounds__(256) void gemm_mfma(
    const unsigned short* __restrict__ A, const unsigned short* __restrict__ BT,
    const float* __restrict__ bias, void* __restrict__ Cout,
    int M, int Ncols, int K) {
  __shared__ short As[128][64];
  __shared__ short Bs[128][64];
  const int tid = threadIdx.x;
  const int lane = tid & 63;
  const int wid = tid >> 6;
  const int wr = wid >> 1, wc = wid & 1;
  const int bm = blockIdx.x * 128;
  const int bn = blockIdx.y * 128;
  const int ar = tid >> 3;
  const int ac = (tid & 7) * 8;

  f32x4 acc[4][4] = {};

  for (int k0 = 0; k0 < K; k0 += 64) {
#pragma unroll
    for (int i = 0; i < 4; i++)
      load_lds16(A + (size_t)(bm + ar + i * 32) * K + k0 + ac, &As[ar + i * 32][ac]);
#pragma unroll
    for (int i = 0; i < 4; i++)
      load_lds16(BT + (size_t)(bn + ar + i * 32) * K + k0 + ac, &Bs[ar + i * 32][ac]);
    __syncthreads();
#pragma unroll
    for (int ks = 0; ks < 2; ks++) {
      bf16x8 af[4], bfm[4];
#pragma unroll
      for (int f = 0; f < 4; f++)
        af[f] = *(const bf16x8*)&As[wr * 64 + f * 16 + (lane & 15)][ks * 32 + (lane >> 4) * 8];
#pragma unroll
      for (int f = 0; f < 4; f++)
        bfm[f] = *(const bf16x8*)&Bs[wc * 64 + f * 16 + (lane & 15)][ks * 32 + (lane >> 4) * 8];
#pragma unroll
      for (int i = 0; i < 4; i++)
#pragma unroll
        for (int j = 0; j < 4; j++)
          acc[i][j] = __builtin_amdgcn_mfma_f32_16x16x32_bf16(af[i], bfm[j], acc[i][j], 0, 0, 0);
    }
    __syncthreads();
  }

  // C/D layout (m89/m91): col = lane&15, row = (lane>>4)*4 + reg
  const int col0 = bn + wc * 64 + (lane & 15);
  const int row0 = bm + wr * 64 + (lane >> 4) * 4;
#pragma unroll
  for (int i = 0; i < 4; i++) {
#pragma unroll
    for (int jf = 0; jf < 4; jf++) {
      int col = col0 + jf * 16;
      float bv = HASBIAS ? bias[col] : 0.f;
#pragma unroll
      for (int j = 0; j < 4; j++) {
        int row = row0 + i * 16 + j;
        if (row < M) {
          float v = acc[i][jf][j] + bv;
          if (RELU) v = fmaxf(v, 0.f);
          if (OUT_BF16)
            ((unsigned short*)Cout)[(size_t)row * Ncols + col] = f2bf(v);
          else
            ((float*)Cout)[(size_t)row * Ncols + col] = v;
        }
      }
    }
  }
}

// x fp32 [NN][518] -> xb bf16 [NN][576] (k-pad zeros; pad rows stale = harmless)
__global__ void convert_x_kernel(const float* __restrict__ x, unsigned short* __restrict__ xb) {
  int t = blockIdx.x * blockDim.x + threadIdx.x;
  if (t >= NN * 288) return;
  int r = t / 288, c = (t % 288) * 2;
  unsigned int o = 0;
  if (c + 1 < DINK) {
    float2 v = *(const float2*)&x[(size_t)r * DINK + c];
    o = (unsigned)f2bf(v.x) | ((unsigned)f2bf(v.y) << 16);
  } else if (c < DINK) {
    o = (unsigned)f2bf(x[(size_t)r * DINK + c]);
  }
  *(unsigned int*)&xb[(size_t)r * KP1 + c] = o;
}

// W [K][Ncols] fp32 -> WT [Ncols][Kpad] bf16 (zero-pad k>=K)
__global__ void convT_kernel(const float* __restrict__ W, unsigned short* __restrict__ WT,
                             int K, int Ncols, int Kpad) {
  int t = blockIdx.x * blockDim.x + threadIdx.x;
  if (t >= Ncols * Kpad) return;
  int n = t / Kpad, k = t % Kpad;
  float v = (k < K) ? W[(size_t)k * Ncols + n] : 0.f;
  WT[(size_t)n * Kpad + k] = f2bf(v);
}

// ---------------- CSR build (counting sort by dst; reused by both layers) ----
__global__ void cnti_kernel(const int* __restrict__ dst, int* __restrict__ cnti, int E) {
  int e = blockIdx.x * blockDim.x + threadIdx.x;
  if (e < E) atomicAdd(&cnti[dst[e]], 1);
}

__global__ void partial_kernel(const int* __restrict__ cnti, int* __restrict__ partial, int n) {
  __shared__ int sh[4];
  int i = blockIdx.x * 256 + threadIdx.x;
  int lane = threadIdx.x & 63, wid = threadIdx.x >> 6;
  int v = (i < n) ? cnti[i] : 0;
#pragma unroll
  for (int off = 32; off; off >>= 1) v += __shfl_xor(v, off);
  if (lane == 0) sh[wid] = v;
  __syncthreads();
  if (threadIdx.x == 0) partial[blockIdx.x] = sh[0] + sh[1] + sh[2] + sh[3];
}

__global__ void scanpartial_kernel(const int* __restrict__ partial, int* __restrict__ poffs,
                                   int* __restrict__ rowptr, int nb) {
  __shared__ int buf[256];
  int t = threadIdx.x;
  int v = (t < nb) ? partial[t] : 0;
  buf[t] = v;
  __syncthreads();
  for (int off = 1; off < 256; off <<= 1) {
    int add = (t >= off) ? buf[t - off] : 0;
    __syncthreads();
    buf[t] += add;
    __syncthreads();
  }
  if (t < nb) poffs[t] = buf[t] - v;   // exclusive
  if (t == 0) rowptr[NN] = EE;
}

__global__ void scatter_scan_kernel(const int* __restrict__ cnti, const int* __restrict__ poffs,
                                    int* __restrict__ rowptr, int* __restrict__ wtr, int n) {
  __shared__ int buf[256];
  int t = threadIdx.x;
  int i = blockIdx.x * 256 + t;
  int v = (i < n) ? cnti[i] : 0;
  buf[t] = v;
  __syncthreads();
  for (int off = 1; off < 256; off <<= 1) {
    int add = (t >= off) ? buf[t - off] : 0;
    __syncthreads();
    buf[t] += add;
    __syncthreads();
  }
  if (i < n) {
    int r = poffs[blockIdx.x] + buf[t] - v;
    rowptr[i] = r;
    wtr[i] = r;
  }
}

__global__ void place_kernel(const int* __restrict__ src, const int* __restrict__ dst,
                             const int* __restrict__ attr, int* __restrict__ wtr,
                             int* __restrict__ csrc, int* __restrict__ cattr, int E) {
  int e = blockIdx.x * blockDim.x + threadIdx.x;
  if (e >= E) return;
  int p = atomicAdd(&wtr[dst[e]], 1);
  csrc[p] = src[e];
  cattr[p] = attr[e];
}

// ---------------- GAT helpers ----------------
__global__ void vtable_kernel(const float* __restrict__ line,
                              const float* __restrict__ att_edge,
                              const float* __restrict__ rel_emb,
                              float* __restrict__ table) {
  __shared__ float ve[32];
  int t = threadIdx.x;  // 64 threads
  if (t < 32) {
    float s = 0.f;
    for (int d = 0; d < 128; d++) s += line[t * 128 + d] * att_edge[d];
    ve[t] = s;
  }
  __syncthreads();
  if (t < 26) {
    float s = 0.f;
    for (int j = 0; j < 32; j++) s += rel_emb[t * 32 + j] * ve[j];
    table[t] = s;
  }
}

// per-node dots with attention vectors; hp is bf16 (lane owns 2 cols)
__global__ void sdots_kernel(const unsigned short* __restrict__ hp,
                             const float* __restrict__ att_src,
                             const float* __restrict__ att_dst,
                             float* __restrict__ ssrc, float* __restrict__ sdst, int n) {
  int wave = (blockIdx.x * blockDim.x + threadIdx.x) >> 6;
  int lane = threadIdx.x & 63;
  if (wave >= n) return;
  unsigned w = *(const unsigned*)&hp[(size_t)wave * DD + lane * 2];
  float v0 = bflo(w), v1 = bfhi(w);
  float a = v0 * att_src[lane * 2] + v1 * att_src[lane * 2 + 1];
  float b = v0 * att_dst[lane * 2] + v1 * att_dst[lane * 2 + 1];
#pragma unroll
  for (int off = 32; off; off >>= 1) {
    a += __shfl_xor(a, off);
    b += __shfl_xor(b, off);
  }
  if (lane == 0) { ssrc[wave] = a; sdst[wave] = b; }
}

// ---------------- fused GAT aggregate: one wave per dst node ----------------
__global__ __launch_bounds__(256) void gat_gather_kernel(
    const int* __restrict__ rowptr, const int* __restrict__ csrc,
    const int* __restrict__ cattr, const float* __restrict__ table,
    const float* __restrict__ ssrc, const float* __restrict__ sdst,
    const unsigned short* __restrict__ hp, const float* __restrict__ bias,
    unsigned short* __restrict__ hout, int n) {
  __shared__ float exs[4][CAP];
  const int wid = threadIdx.x >> 6, lane = threadIdx.x & 63;
  const int node = (blockIdx.x * blockDim.x + threadIdx.x) >> 6;
  if (node >= n) return;
  const int j0 = rowptr[node], j1 = rowptr[node + 1];
  const int deg = j1 - j0;
  const float sd = sdst[node];
  float den = 0.f, esum = 0.f;
  for (int j = j0 + lane; j < j1; j += 64) {
    float t = table[cattr[j]];
    float l = ssrc[csrc[j]] + sd + t;
    l = (l > 0.f) ? l : NEG_SLOPE * l;
    float ex = expf(l);
    int k = j - j0;
    if (k < CAP) exs[wid][k] = ex;
    den += ex; esum += t;
  }
#pragma unroll
  for (int off = 32; off; off >>= 1) {
    den += __shfl_xor(den, off);
    esum += __shfl_xor(esum, off);
  }
  // self-loop (edge vector = mean of incoming -> table-space mean)
  float tl = esum / fmaxf((float)deg, 1.f);
  float ll = ssrc[node] + sd + tl;
  ll = (ll > 0.f) ? ll : NEG_SLOPE * ll;
  float exl = expf(ll);
  den += exl;
  const float inv = 1.f / (den + 1e-16f);
  // pass 2: lane owns cols c, c+1 (one dword of bf16 per row)
  const int c = lane * 2;
  float2 acc;
  {
    unsigned w = *(const unsigned*)&hp[(size_t)node * DD + c];
    float a = exl * inv;
    acc.x = a * bflo(w); acc.y = a * bfhi(w);
  }
  for (int j = j0; j < j1; j++) {
    int k = j - j0;
    float ex;
    if (k < CAP) ex = exs[wid][k];
    else {  // cold fallback, deg > CAP
      float t = table[cattr[j]];
      float l = ssrc[csrc[j]] + sd + t;
      l = (l > 0.f) ? l : NEG_SLOPE * l;
      ex = expf(l);
    }
    float a = ex * inv;
    unsigned w = *(const unsigned*)&hp[(size_t)csrc[j] * DD + c];
    acc.x += a * bflo(w); acc.y += a * bfhi(w);
  }
  acc.x = fmaxf(acc.x + bias[c], 0.f);
  acc.y = fmaxf(acc.y + bias[c + 1], 0.f);
  unsigned o = (unsigned)f2bf(acc.x) | ((unsigned)f2bf(acc.y) << 16);
  *(unsigned*)&hout[(size_t)node * DD + c] = o;
}

__global__ void pool_kernel(const unsigned short* __restrict__ h, float* __restrict__ g, int n) {
  __shared__ float sh[128];
  int tid = threadIdx.x;
  int cp = tid & 63, half = tid >> 6;     // 4 row-groups, lane owns 2 cols
  float sx = 0.f, sy = 0.f;
  for (int r = blockIdx.x * 4 + half; r < n; r += gridDim.x * 4) {
    unsigned w = *(const unsigned*)&h[(size_t)r * DD + cp * 2];
    sx += bflo(w); sy += bfhi(w);
  }
  if (half == 0) { sh[cp * 2] = sx; sh[cp * 2 + 1] = sy; }
  __syncthreads();
  if (half == 1) { sh[cp * 2] += sx; sh[cp * 2 + 1] += sy; }
  __syncthreads();
  if (half == 2) { sh[cp * 2] += sx; sh[cp * 2 + 1] += sy; }
  __syncthreads();
  if (half == 3) {
    atomicAdd(&g[cp * 2], sh[cp * 2] + sx);
    atomicAdd(&g[cp * 2 + 1], sh[cp * 2 + 1] + sy);
  }
}

__global__ void readout_kernel(const float* __restrict__ g, const float* __restrict__ Wr1,
                               const float* __restrict__ br1, const float* __restrict__ Wr2,
                               const float* __restrict__ br2, float* __restrict__ out,
                               float inv_n) {
  __shared__ float gl[128];
  __shared__ float m[64];
  int t = threadIdx.x;  // 64 threads
  gl[t] = g[t] * inv_n;
  gl[t + 64] = g[t + 64] * inv_n;
  __syncthreads();
  {
    float acc = br1[t];
    for (int c = 0; c < 128; c++) acc += gl[c] * Wr1[c * 64 + t];
    m[t] = fmaxf(acc, 0.f);
  }
  __syncthreads();
  if (t < 32) {
    float acc = br2[t];
    for (int j = 0; j < 64; j++) acc += m[j] * Wr2[j * 32 + t];
    out[t] = acc;
  }
}

// ---------------- launch ----------------
extern "C" void kernel_launch(void* const* d_in, const int* in_sizes, int n_in,
                              void* d_out, int out_size, void* d_ws, size_t ws_size,
                              hipStream_t stream) {
  const float* x     = (const float*)d_in[0];
  const int*   ei    = (const int*)d_in[1];
  const int*   eattr = (const int*)d_in[2];
  const float* W1 = (const float*)d_in[3];
  const float* b1 = (const float*)d_in[4];
  const float* W2 = (const float*)d_in[5];
  const float* b2 = (const float*)d_in[6];
  const float* rel_emb = (const float*)d_in[7];
  const float* lin[2]      = {(const float*)d_in[8],  (const float*)d_in[14]};
  const float* att_src[2]  = {(const float*)d_in[9],  (const float*)d_in[15]};
  const float* att_dst[2]  = {(const float*)d_in[10], (const float*)d_in[16]};
  const float* att_edge[2] = {(const float*)d_in[11], (const float*)d_in[17]};
  const float* line[2]     = {(const float*)d_in[12], (const float*)d_in[18]};
  const float* bias[2]     = {(const float*)d_in[13], (const float*)d_in[19]};
  const float* Wr1 = (const float*)d_in[20];
  const float* br1 = (const float*)d_in[21];
  const float* Wr2 = (const float*)d_in[22];
  const float* br2 = (const float*)d_in[23];
  float* out = (float*)d_out;

  const int* srcv = ei;
  const int* dstv = ei + EE;

  // Workspace overlay (byte offsets):
  //  [0 .. 57.66M)      xb bf16 [MP][576]  (encoder only; dead after GEMM1)
  //  [0 .. 12.8M)       hA bf16 [MP][128]  (GEMM2 output onward; aliases dead xb)
  //  [12.9M .. 25.7M)   hp bf16 [MP][128]  (layer phase)
  //  [25.8M .. 38.6M)   hB bf16 [MP][128]  (layer phase)
  //  [57.66M .. 83.28M) mid bf16 [MP][256] (dead after GEMM2)
  //  [83.3M ..)         weightsT, CSR arrays, small vectors
  char* wsb = (char*)d_ws;
  unsigned short* xb  = (unsigned short*)(wsb + 0);
  unsigned short* hA  = (unsigned short*)(wsb + 0);
  unsigned short* hp  = (unsigned short*)(wsb + 12900000);
  unsigned short* hB  = (unsigned short*)(wsb + 25800000);
  unsigned short* mid = (unsigned short*)(wsb + 57655296);
  unsigned short* W1T = (unsigned short*)(wsb + 83300000);
  unsigned short* W2T = (unsigned short*)(wsb + 83600000);
  unsigned short* lin1T = (unsigned short*)(wsb + 83700000);
  unsigned short* lin2T = (unsigned short*)(wsb + 83740000);
  int* rowptr  = (int*)(wsb + 83800000);
  int* wtr     = (int*)(wsb + 84000008);
  int* cnti    = (int*)(wsb + 84200008);
  int* csrc    = (int*)(wsb + 84400008);
  int* cattr   = (int*)(wsb + 86800008);
  float* ssrc  = (float*)(wsb + 89200008);
  float* sdst  = (float*)(wsb + 89400008);
  int* partial = (int*)(wsb + 89600008);
  int* poffs   = (int*)(wsb + 89601032);
  float* table = (float*)(wsb + 89602056);
  float* g     = (float*)(wsb + 89602184);

  dim3 blk(256);
  const int NBLK = (NN + 255) / 256;  // 196

  hipMemsetAsync(cnti, 0, NN * sizeof(int), stream);
  hipMemsetAsync(g, 0, 128 * sizeof(float), stream);

  // encoder: convert + bf16 MFMA GEMMs
  convert_x_kernel<<<dim3((NN * 288 + 255) / 256), blk, 0, stream>>>(x, xb);
  convT_kernel<<<dim3((256 * KP1 + 255) / 256), blk, 0, stream>>>(W1, W1T, DINK, 256, KP1);
  convT_kernel<<<dim3((128 * 256 + 255) / 256), blk, 0, stream>>>(W2, W2T, 256, 128, 256);
  convT_kernel<<<dim3((128 * 128 + 255) / 256), blk, 0, stream>>>(lin[0], lin1T, 128, 128, 128);
  convT_kernel<<<dim3((128 * 128 + 255) / 256), blk, 0, stream>>>(lin[1], lin2T, 128, 128, 128);
  gemm_mfma<true, true, true><<<dim3(391, 2), blk, 0, stream>>>(xb, W1T, b1, mid, NN, 256, KP1);
  gemm_mfma<true, false, true><<<dim3(391, 1), blk, 0, stream>>>(mid, W2T, b2, hA, NN, 128, 256);

  // CSR build (once; both layers reuse)
  cnti_kernel<<<dim3((EE + 255) / 256), blk, 0, stream>>>(dstv, cnti, EE);
  partial_kernel<<<dim3(NBLK), blk, 0, stream>>>(cnti, partial, NN);
  scanpartial_kernel<<<1, 256, 0, stream>>>(partial, poffs, rowptr, NBLK);
  scatter_scan_kernel<<<dim3(NBLK), blk, 0, stream>>>(cnti, poffs, rowptr, wtr, NN);
  place_kernel<<<dim3((EE + 255) / 256), blk, 0, stream>>>(srcv, dstv, eattr, wtr, csrc, cattr, EE);

  const unsigned short* lint[2] = {lin1T, lin2T};
  const unsigned short* hin = hA;
  unsigned short* hout = hB;
  for (int L = 0; L < 2; ++L) {
    gemm_mfma<true, false, false><<<dim3(391, 1), blk, 0, stream>>>(hin, lint[L], nullptr, hp, NN, 128, 128);
    vtable_kernel<<<1, 64, 0, stream>>>(line[L], att_edge[L], rel_emb, table);
    sdots_kernel<<<dim3((NN * 64 + 255) / 256), blk, 0, stream>>>(hp, att_src[L], att_dst[L], ssrc, sdst, NN);
    gat_gather_kernel<<<dim3((NN * 64 + 255) / 256), blk, 0, stream>>>(
        rowptr, csrc, cattr, table, ssrc, sdst, hp, bias[L], hout, NN);
    const unsigned short* t = hin; hin = hout; hout = (unsigned short*)t;
  }

  pool_kernel<<<dim3(256), blk, 0, stream>>>(hin, g, NN);
  readout_kernel<<<1, 64, 0, stream>>>(g, Wr1, br1, Wr2, br2, out, 1.0f / NN);
}

// Round 7
// 325.660 us; speedup vs baseline: 3.7203x; 1.2631x over previous
//
#include <hip/hip_runtime.h>
#include <hip/hip_bf16.h>

#define NN   50000
#define EE   600000
#define DINK 518
#define KP1  576          // padded K for encoder GEMM1 (9*64)
#define MP   50048        // padded rows (391*128)
#define DD   128
#define NEG_SLOPE 0.2f
#define CAP  256          // per-wave LDS stash (max in-degree fast path)

typedef short bf16x8 __attribute__((ext_vector_type(8)));
typedef float f32x4 __attribute__((ext_vector_type(4)));

typedef const __attribute__((address_space(1))) void* gp1_t;
typedef __attribute__((address_space(3))) void* lp3_t;

__device__ __forceinline__ void load_lds16(const void* g, void* l) {
  __builtin_amdgcn_global_load_lds((gp1_t)g, (lp3_t)l, 16, 0, 0);
}

__device__ __forceinline__ unsigned short f2bf(float f) {
  union { float f; unsigned u; } q; q.f = f;
  unsigned u = q.u + 0x7FFFu + ((q.u >> 16) & 1u);   // RNE
  return (unsigned short)(u >> 16);
}
__device__ __forceinline__ float bflo(unsigned u) {
  union { unsigned u; float f; } q; q.u = u << 16; return q.f;
}
__device__ __forceinline__ float bfhi(unsigned u) {
  union { unsigned u; float f; } q; q.u = u & 0xFFFF0000u; return q.f;
}

// ---------------- bf16 MFMA GEMM:  C = act(A @ BT^T [+ bias]) ----------------
// A:[Mpad][K] bf16 row-major; BT:[Ncols][K] bf16. 128x128 tile, BK=64, 4 waves.
template<bool OUT_BF16, bool RELU, bool HASBIAS>
__global__ __launch_bounds__(256) void gemm_mfma(
    const unsigned short* __restrict__ A, const unsigned short* __restrict__ BT,
    const float* __restrict__ bias, void* __restrict__ Cout,
    int M, int Ncols, int K) {
  __shared__ short As[128][64];
  __shared__ short Bs[128][64];
  const int tid = threadIdx.x;
  const int lane = tid & 63;
  const int wid = tid >> 6;
  const int wr = wid >> 1, wc = wid & 1;
  const int bm = blockIdx.x * 128;
  const int bn = blockIdx.y * 128;
  const int ar = tid >> 3;
  const int ac = (tid & 7) * 8;

  f32x4 acc[4][4] = {};

  for (int k0 = 0; k0 < K; k0 += 64) {
#pragma unroll
    for (int i = 0; i < 4; i++)
      load_lds16(A + (size_t)(bm + ar + i * 32) * K + k0 + ac, &As[ar + i * 32][ac]);
#pragma unroll
    for (int i = 0; i < 4; i++)
      load_lds16(BT + (size_t)(bn + ar + i * 32) * K + k0 + ac, &Bs[ar + i * 32][ac]);
    __syncthreads();
#pragma unroll
    for (int ks = 0; ks < 2; ks++) {
      bf16x8 af[4], bfm[4];
#pragma unroll
      for (int f = 0; f < 4; f++)
        af[f] = *(const bf16x8*)&As[wr * 64 + f * 16 + (lane & 15)][ks * 32 + (lane >> 4) * 8];
#pragma unroll
      for (int f = 0; f < 4; f++)
        bfm[f] = *(const bf16x8*)&Bs[wc * 64 + f * 16 + (lane & 15)][ks * 32 + (lane >> 4) * 8];
#pragma unroll
      for (int i = 0; i < 4; i++)
#pragma unroll
        for (int j = 0; j < 4; j++)
          acc[i][j] = __builtin_amdgcn_mfma_f32_16x16x32_bf16(af[i], bfm[j], acc[i][j], 0, 0, 0);
    }
    __syncthreads();
  }

  // C/D layout (m89/m91): col = lane&15, row = (lane>>4)*4 + reg
  const int col0 = bn + wc * 64 + (lane & 15);
  const int row0 = bm + wr * 64 + (lane >> 4) * 4;
#pragma unroll
  for (int i = 0; i < 4; i++) {
#pragma unroll
    for (int jf = 0; jf < 4; jf++) {
      int col = col0 + jf * 16;
      float bv = HASBIAS ? bias[col] : 0.f;
#pragma unroll
      for (int j = 0; j < 4; j++) {
        int row = row0 + i * 16 + j;
        if (row < M) {
          float v = acc[i][jf][j] + bv;
          if (RELU) v = fmaxf(v, 0.f);
          if (OUT_BF16)
            ((unsigned short*)Cout)[(size_t)row * Ncols + col] = f2bf(v);
          else
            ((float*)Cout)[(size_t)row * Ncols + col] = v;
        }
      }
    }
  }
}

// x fp32 [NN][518] -> xb bf16 [NN][576] (k-pad zeros; pad rows stale = harmless)
__global__ void convert_x_kernel(const float* __restrict__ x, unsigned short* __restrict__ xb) {
  int t = blockIdx.x * blockDim.x + threadIdx.x;
  if (t >= NN * 288) return;
  int r = t / 288, c = (t % 288) * 2;
  unsigned int o = 0;
  if (c + 1 < DINK) {
    float2 v = *(const float2*)&x[(size_t)r * DINK + c];
    o = (unsigned)f2bf(v.x) | ((unsigned)f2bf(v.y) << 16);
  } else if (c < DINK) {
    o = (unsigned)f2bf(x[(size_t)r * DINK + c]);
  }
  *(unsigned int*)&xb[(size_t)r * KP1 + c] = o;
}

// ---------------- combined weight prep: 4 transposed-bf16 weights + 2 tables -
__device__ __forceinline__ void convT_body(const float* __restrict__ W,
                                           unsigned short* __restrict__ WT,
                                           int K, int Ncols, int Kpad, int t) {
  int n = t / Kpad, k = t % Kpad;
  float v = (k < K) ? W[(size_t)k * Ncols + n] : 0.f;
  WT[(size_t)n * Kpad + k] = f2bf(v);
}

__global__ __launch_bounds__(256) void prep_kernel(
    const float* __restrict__ W1, const float* __restrict__ W2,
    const float* __restrict__ l1, const float* __restrict__ l2,
    const float* __restrict__ le1, const float* __restrict__ le2,
    const float* __restrict__ ae1, const float* __restrict__ ae2,
    const float* __restrict__ rel_emb,
    unsigned short* __restrict__ W1T, unsigned short* __restrict__ W2T,
    unsigned short* __restrict__ l1T, unsigned short* __restrict__ l2T,
    float* __restrict__ tables) {
  const int b = blockIdx.x, tid = threadIdx.x;
  if (b < 576) { convT_body(W1, W1T, DINK, 256, KP1, b * 256 + tid); return; }
  if (b < 704) { convT_body(W2, W2T, 256, 128, 256, (b - 576) * 256 + tid); return; }
  if (b < 768) { convT_body(l1, l1T, 128, 128, 128, (b - 704) * 256 + tid); return; }
  if (b < 832) { convT_body(l2, l2T, 128, 128, 128, (b - 768) * 256 + tid); return; }
  // tables[layer][r] = rel_emb[r] . (line @ att_edge)
  const int layer = b - 832;
  const float* line = layer ? le2 : le1;
  const float* ae   = layer ? ae2 : ae1;
  __shared__ float ve[32];
  if (tid < 32) {
    float s = 0.f;
    for (int d = 0; d < 128; d++) s += line[tid * 128 + d] * ae[d];
    ve[tid] = s;
  }
  __syncthreads();
  if (tid < 26) {
    float s = 0.f;
    for (int j = 0; j < 32; j++) s += rel_emb[tid * 32 + j] * ve[j];
    tables[layer * 32 + tid] = s;
  }
}

// ---------------- CSR build (counting sort by dst; reused by both layers) ----
__global__ void cnti_kernel(const int* __restrict__ dst, int* __restrict__ cnti, int E) {
  int e = blockIdx.x * blockDim.x + threadIdx.x;
  if (e < E) atomicAdd(&cnti[dst[e]], 1);
}

__global__ void partial_kernel(const int* __restrict__ cnti, int* __restrict__ partial, int n) {
  __shared__ int sh[4];
  int i = blockIdx.x * 256 + threadIdx.x;
  int lane = threadIdx.x & 63, wid = threadIdx.x >> 6;
  int v = (i < n) ? cnti[i] : 0;
#pragma unroll
  for (int off = 32; off; off >>= 1) v += __shfl_xor(v, off);
  if (lane == 0) sh[wid] = v;
  __syncthreads();
  if (threadIdx.x == 0) partial[blockIdx.x] = sh[0] + sh[1] + sh[2] + sh[3];
}

__global__ void scanpartial_kernel(const int* __restrict__ partial, int* __restrict__ poffs,
                                   int* __restrict__ rowptr, int nb) {
  __shared__ int buf[256];
  int t = threadIdx.x;
  int v = (t < nb) ? partial[t] : 0;
  buf[t] = v;
  __syncthreads();
  for (int off = 1; off < 256; off <<= 1) {
    int add = (t >= off) ? buf[t - off] : 0;
    __syncthreads();
    buf[t] += add;
    __syncthreads();
  }
  if (t < nb) poffs[t] = buf[t] - v;   // exclusive
  if (t == 0) rowptr[NN] = EE;
}

__global__ void scatter_scan_kernel(const int* __restrict__ cnti, const int* __restrict__ poffs,
                                    int* __restrict__ rowptr, int* __restrict__ wtr, int n) {
  __shared__ int buf[256];
  int t = threadIdx.x;
  int i = blockIdx.x * 256 + t;
  int v = (i < n) ? cnti[i] : 0;
  buf[t] = v;
  __syncthreads();
  for (int off = 1; off < 256; off <<= 1) {
    int add = (t >= off) ? buf[t - off] : 0;
    __syncthreads();
    buf[t] += add;
    __syncthreads();
  }
  if (i < n) {
    int r = poffs[blockIdx.x] + buf[t] - v;
    rowptr[i] = r;
    wtr[i] = r;
  }
}

__global__ void place_kernel(const int* __restrict__ src, const int* __restrict__ dst,
                             const int* __restrict__ attr, int* __restrict__ wtr,
                             int* __restrict__ csrc, int* __restrict__ cattr, int E) {
  int e = blockIdx.x * blockDim.x + threadIdx.x;
  if (e >= E) return;
  int p = atomicAdd(&wtr[dst[e]], 1);
  csrc[p] = src[e];
  cattr[p] = attr[e];
}

// per-node dots with attention vectors; hp is bf16 (lane owns 2 cols)
__global__ void sdots_kernel(const unsigned short* __restrict__ hp,
                             const float* __restrict__ att_src,
                             const float* __restrict__ att_dst,
                             float* __restrict__ ssrc, float* __restrict__ sdst, int n) {
  int wave = (blockIdx.x * blockDim.x + threadIdx.x) >> 6;
  int lane = threadIdx.x & 63;
  if (wave >= n) return;
  unsigned w = *(const unsigned*)&hp[(size_t)wave * DD + lane * 2];
  float v0 = bflo(w), v1 = bfhi(w);
  float a = v0 * att_src[lane * 2] + v1 * att_src[lane * 2 + 1];
  float b = v0 * att_dst[lane * 2] + v1 * att_dst[lane * 2 + 1];
#pragma unroll
  for (int off = 32; off; off >>= 1) {
    a += __shfl_xor(a, off);
    b += __shfl_xor(b, off);
  }
  if (lane == 0) { ssrc[wave] = a; sdst[wave] = b; }
}

// ---------------- fused GAT aggregate: one wave per dst node ----------------
// pass1: lane-parallel logits -> exp + src row-offsets stashed in LDS, reduce.
// pass2: addresses come from LDS (no global dependent chain), unrolled x4 for MLP.
__global__ __launch_bounds__(256) void gat_gather_kernel(
    const int* __restrict__ rowptr, const int* __restrict__ csrc,
    const int* __restrict__ cattr, const float* __restrict__ table,
    const float* __restrict__ ssrc, const float* __restrict__ sdst,
    const unsigned short* __restrict__ hp, const float* __restrict__ bias,
    unsigned short* __restrict__ hout, int n) {
  __shared__ float exs[4][CAP];
  __shared__ int   srcs[4][CAP];
  const int wid = threadIdx.x >> 6, lane = threadIdx.x & 63;
  const int node = (blockIdx.x * blockDim.x + threadIdx.x) >> 6;
  if (node >= n) return;
  const int j0 = rowptr[node], j1 = rowptr[node + 1];
  const int deg = j1 - j0;
  const float sd = sdst[node];
  float den = 0.f, esum = 0.f;
  for (int j = j0 + lane; j < j1; j += 64) {
    int s = csrc[j];
    float t = table[cattr[j]];
    float l = ssrc[s] + sd + t;
    l = (l > 0.f) ? l : NEG_SLOPE * l;
    float ex = expf(l);
    int k = j - j0;
    if (k < CAP) { exs[wid][k] = ex; srcs[wid][k] = s * DD; }
    den += ex; esum += t;
  }
#pragma unroll
  for (int off = 32; off; off >>= 1) {
    den += __shfl_xor(den, off);
    esum += __shfl_xor(esum, off);
  }
  // self-loop (edge vector = mean of incoming -> table-space mean)
  float tl = esum / fmaxf((float)deg, 1.f);
  float ll = ssrc[node] + sd + tl;
  ll = (ll > 0.f) ? ll : NEG_SLOPE * ll;
  float exl = expf(ll);
  den += exl;
  const float inv = 1.f / (den + 1e-16f);
  // pass 2: lane owns cols c, c+1 (one dword of bf16 per row)
  const int c = lane * 2;
  float2 acc;
  {
    unsigned w = *(const unsigned*)&hp[(size_t)node * DD + c];
    float a = exl * inv;
    acc.x = a * bflo(w); acc.y = a * bfhi(w);
  }
  const int m = deg < CAP ? deg : CAP;
  int k = 0;
  for (; k + 4 <= m; k += 4) {
    int b0 = srcs[wid][k], b1 = srcs[wid][k + 1];
    int b2 = srcs[wid][k + 2], b3 = srcs[wid][k + 3];
    float a0 = exs[wid][k] * inv, a1 = exs[wid][k + 1] * inv;
    float a2 = exs[wid][k + 2] * inv, a3 = exs[wid][k + 3] * inv;
    unsigned w0 = *(const unsigned*)&hp[(size_t)(b0 + c)];
    unsigned w1 = *(const unsigned*)&hp[(size_t)(b1 + c)];
    unsigned w2 = *(const unsigned*)&hp[(size_t)(b2 + c)];
    unsigned w3 = *(const unsigned*)&hp[(size_t)(b3 + c)];
    acc.x += a0 * bflo(w0) + a1 * bflo(w1) + a2 * bflo(w2) + a3 * bflo(w3);
    acc.y += a0 * bfhi(w0) + a1 * bfhi(w1) + a2 * bfhi(w2) + a3 * bfhi(w3);
  }
  for (; k < m; k++) {
    int b0 = srcs[wid][k];
    float a0 = exs[wid][k] * inv;
    unsigned w0 = *(const unsigned*)&hp[(size_t)(b0 + c)];
    acc.x += a0 * bflo(w0); acc.y += a0 * bfhi(w0);
  }
  for (int j = j0 + CAP; j < j1; j++) {  // cold fallback, deg > CAP
    int s = csrc[j];
    float t = table[cattr[j]];
    float l = ssrc[s] + sd + t;
    l = (l > 0.f) ? l : NEG_SLOPE * l;
    float a0 = expf(l) * inv;
    unsigned w0 = *(const unsigned*)&hp[(size_t)s * DD + c];
    acc.x += a0 * bflo(w0); acc.y += a0 * bfhi(w0);
  }
  acc.x = fmaxf(acc.x + bias[c], 0.f);
  acc.y = fmaxf(acc.y + bias[c + 1], 0.f);
  unsigned o = (unsigned)f2bf(acc.x) | ((unsigned)f2bf(acc.y) << 16);
  *(unsigned*)&hout[(size_t)node * DD + c] = o;
}

__global__ void pool_kernel(const unsigned short* __restrict__ h, float* __restrict__ g, int n) {
  __shared__ float sh[128];
  int tid = threadIdx.x;
  int cp = tid & 63, half = tid >> 6;     // 4 row-groups, lane owns 2 cols
  float sx = 0.f, sy = 0.f;
  for (int r = blockIdx.x * 4 + half; r < n; r += gridDim.x * 4) {
    unsigned w = *(const unsigned*)&h[(size_t)r * DD + cp * 2];
    sx += bflo(w); sy += bfhi(w);
  }
  if (half == 0) { sh[cp * 2] = sx; sh[cp * 2 + 1] = sy; }
  __syncthreads();
  if (half == 1) { sh[cp * 2] += sx; sh[cp * 2 + 1] += sy; }
  __syncthreads();
  if (half == 2) { sh[cp * 2] += sx; sh[cp * 2 + 1] += sy; }
  __syncthreads();
  if (half == 3) {
    atomicAdd(&g[cp * 2], sh[cp * 2] + sx);
    atomicAdd(&g[cp * 2 + 1], sh[cp * 2 + 1] + sy);
  }
}

__global__ void readout_kernel(const float* __restrict__ g, const float* __restrict__ Wr1,
                               const float* __restrict__ br1, const float* __restrict__ Wr2,
                               const float* __restrict__ br2, float* __restrict__ out,
                               float inv_n) {
  __shared__ float gl[128];
  __shared__ float m[64];
  int t = threadIdx.x;  // 64 threads
  gl[t] = g[t] * inv_n;
  gl[t + 64] = g[t + 64] * inv_n;
  __syncthreads();
  {
    float acc = br1[t];
    for (int c = 0; c < 128; c++) acc += gl[c] * Wr1[c * 64 + t];
    m[t] = fmaxf(acc, 0.f);
  }
  __syncthreads();
  if (t < 32) {
    float acc = br2[t];
    for (int j = 0; j < 64; j++) acc += m[j] * Wr2[j * 32 + t];
    out[t] = acc;
  }
}

// ---------------- launch ----------------
extern "C" void kernel_launch(void* const* d_in, const int* in_sizes, int n_in,
                              void* d_out, int out_size, void* d_ws, size_t ws_size,
                              hipStream_t stream) {
  const float* x     = (const float*)d_in[0];
  const int*   ei    = (const int*)d_in[1];
  const int*   eattr = (const int*)d_in[2];
  const float* W1 = (const float*)d_in[3];
  const float* b1 = (const float*)d_in[4];
  const float* W2 = (const float*)d_in[5];
  const float* b2 = (const float*)d_in[6];
  const float* rel_emb = (const float*)d_in[7];
  const float* lin[2]      = {(const float*)d_in[8],  (const float*)d_in[14]};
  const float* att_src[2]  = {(const float*)d_in[9],  (const float*)d_in[15]};
  const float* att_dst[2]  = {(const float*)d_in[10], (const float*)d_in[16]};
  const float* att_edge[2] = {(const float*)d_in[11], (const float*)d_in[17]};
  const float* line[2]     = {(const float*)d_in[12], (const float*)d_in[18]};
  const float* bias[2]     = {(const float*)d_in[13], (const float*)d_in[19]};
  const float* Wr1 = (const float*)d_in[20];
  const float* br1 = (const float*)d_in[21];
  const float* Wr2 = (const float*)d_in[22];
  const float* br2 = (const float*)d_in[23];
  float* out = (float*)d_out;

  const int* srcv = ei;
  const int* dstv = ei + EE;

  // Workspace overlay (byte offsets):
  //  [0 .. 57.66M)      xb bf16 [MP][576]  (encoder only; dead after GEMM1)
  //  [0 .. 12.8M)       hA bf16 [MP][128]  (GEMM2 output onward; aliases dead xb)
  //  [12.9M .. 25.7M)   hp bf16 [MP][128]  (layer phase)
  //  [25.8M .. 38.6M)   hB bf16 [MP][128]  (layer phase)
  //  [57.66M .. 83.28M) mid bf16 [MP][256] (dead after GEMM2)
  //  [83.3M ..)         weightsT, CSR arrays, small vectors
  char* wsb = (char*)d_ws;
  unsigned short* xb  = (unsigned short*)(wsb + 0);
  unsigned short* hA  = (unsigned short*)(wsb + 0);
  unsigned short* hp  = (unsigned short*)(wsb + 12900000);
  unsigned short* hB  = (unsigned short*)(wsb + 25800000);
  unsigned short* mid = (unsigned short*)(wsb + 57655296);
  unsigned short* W1T = (unsigned short*)(wsb + 83300000);
  unsigned short* W2T = (unsigned short*)(wsb + 83600000);
  unsigned short* lin1T = (unsigned short*)(wsb + 83700000);
  unsigned short* lin2T = (unsigned short*)(wsb + 83740000);
  int* rowptr  = (int*)(wsb + 83800000);
  int* wtr     = (int*)(wsb + 84000008);
  int* cnti    = (int*)(wsb + 84200008);
  int* csrc    = (int*)(wsb + 84400008);
  int* cattr   = (int*)(wsb + 86800008);
  float* ssrc  = (float*)(wsb + 89200008);
  float* sdst  = (float*)(wsb + 89400008);
  int* partial = (int*)(wsb + 89600008);
  int* poffs   = (int*)(wsb + 89601032);
  float* tables = (float*)(wsb + 89602056);   // [2][32]
  float* g      = (float*)(wsb + 89602312);

  dim3 blk(256);
  const int NBLK = (NN + 255) / 256;  // 196

  hipMemsetAsync(cnti, 0, NN * sizeof(int), stream);
  hipMemsetAsync(g, 0, 128 * sizeof(float), stream);

  // encoder prep: convert x + all weight transposes + both attention tables
  convert_x_kernel<<<dim3((NN * 288 + 255) / 256), blk, 0, stream>>>(x, xb);
  prep_kernel<<<dim3(834), blk, 0, stream>>>(
      W1, W2, lin[0], lin[1], line[0], line[1], att_edge[0], att_edge[1], rel_emb,
      W1T, W2T, lin1T, lin2T, tables);
  gemm_mfma<true, true, true><<<dim3(391, 2), blk, 0, stream>>>(xb, W1T, b1, mid, NN, 256, KP1);
  gemm_mfma<true, false, true><<<dim3(391, 1), blk, 0, stream>>>(mid, W2T, b2, hA, NN, 128, 256);

  // CSR build (once; both layers reuse)
  cnti_kernel<<<dim3((EE + 255) / 256), blk, 0, stream>>>(dstv, cnti, EE);
  partial_kernel<<<dim3(NBLK), blk, 0, stream>>>(cnti, partial, NN);
  scanpartial_kernel<<<1, 256, 0, stream>>>(partial, poffs, rowptr, NBLK);
  scatter_scan_kernel<<<dim3(NBLK), blk, 0, stream>>>(cnti, poffs, rowptr, wtr, NN);
  place_kernel<<<dim3((EE + 255) / 256), blk, 0, stream>>>(srcv, dstv, eattr, wtr, csrc, cattr, EE);

  const unsigned short* lint[2] = {lin1T, lin2T};
  const unsigned short* hin = hA;
  unsigned short* hout = hB;
  for (int L = 0; L < 2; ++L) {
    gemm_mfma<true, false, false><<<dim3(391, 1), blk, 0, stream>>>(hin, lint[L], nullptr, hp, NN, 128, 128);
    sdots_kernel<<<dim3((NN * 64 + 255) / 256), blk, 0, stream>>>(hp, att_src[L], att_dst[L], ssrc, sdst, NN);
    gat_gather_kernel<<<dim3((NN * 64 + 255) / 256), blk, 0, stream>>>(
        rowptr, csrc, cattr, tables + L * 32, ssrc, sdst, hp, bias[L], hout, NN);
    const unsigned short* t = hin; hin = hout; hout = (unsigned short*)t;
  }

  pool_kernel<<<dim3(256), blk, 0, stream>>>(hin, g, NN);
  readout_kernel<<<1, 64, 0, stream>>>(g, Wr1, br1, Wr2, br2, out, 1.0f / NN);
}